// Round 8
// baseline (209.525 us; speedup 1.0000x reference)
//
#include <hip/hip_runtime.h>
#include <cstdint>
#include <cstddef>

#define B_ 256
#define N_ 512
#define RCAP 72     // neighbor list stride (u16), padded with dummy row 512
#define SB   40     // bf16 row stride: 80B rows -> b128 quad = (5*row + d) & 7

typedef unsigned short u16;

// ---------------- workspace layout (bytes), ~20 MB ----------------
constexpr size_t O_COLIDX = 0;          // u16 [131072*72]
constexpr size_t O_ROWCNT = 18874368;   // int [131072]  (stores nch = chunk count)
constexpr size_t O_DIS    = 19398656;   // f32 [131072]
constexpr size_t O_DIAG   = 19922944;   // f32 [131072]

// ---------------- pass 1: read adj ONCE (high occupancy), build padded CSR ----------
__global__ __launch_bounds__(256) void build_sparse(
    const float* __restrict__ adj, u16* __restrict__ colidx,
    int* __restrict__ rowcnt, float* __restrict__ dis, float* __restrict__ diagv)
{
    int row  = blockIdx.x * 4 + (threadIdx.x >> 6);
    int lane = threadIdx.x & 63;
    int i    = row & (N_ - 1);
    const float4* arow = (const float4*)(adj + (size_t)row * N_);
    float4 v0 = arow[lane];
    float4 v1 = arow[lane + 64];
    float vals[8] = {v0.x, v0.y, v0.z, v0.w, v1.x, v1.y, v1.z, v1.w};

    float sum = 0.f, dloc = 0.f;
    int cnt = 0;
    #pragma unroll
    for (int k = 0; k < 8; ++k) {
        int jc = (k < 4) ? (lane * 4 + k) : (256 + lane * 4 + (k - 4));
        float v = vals[k];
        if (jc == i) dloc = v;
        else { sum += v; if (v != 0.f) ++cnt; }
    }
    int pre = cnt;
    #pragma unroll
    for (int d = 1; d < 64; d <<= 1) { int y = __shfl_up(pre, d, 64); if (lane >= d) pre += y; }
    int excl  = pre - cnt;
    int total = __shfl(pre, 63, 64);
    #pragma unroll
    for (int d = 32; d > 0; d >>= 1) { sum += __shfl_xor(sum, d, 64); dloc += __shfl_xor(dloc, d, 64); }

    u16* cb = colidx + (size_t)row * RCAP;
    int c2 = 0;
    #pragma unroll
    for (int k = 0; k < 8; ++k) {
        int jc = (k < 4) ? (lane * 4 + k) : (256 + lane * 4 + (k - 4));
        float v = vals[k];
        if (jc != i && v != 0.f) { int p = excl + c2; if (p < RCAP) cb[p] = (u16)jc; ++c2; }
    }
    int base = total > RCAP ? RCAP : total;
    int p1 = base + lane;      if (p1 < RCAP) cb[p1] = (u16)N_;
    int p2 = base + 64 + lane; if (p2 < RCAP) cb[p2] = (u16)N_;
    if (lane == 0) {
        rowcnt[row] = (base + 7) >> 3;                 // chunk count
        dis[row]    = rsqrtf(fmaxf(1.f, sum + 1.f));
        diagv[row]  = dloc;
    }
}

// ---------------- bf16 helpers ----------------
__device__ __forceinline__ float blo(unsigned u) { return __uint_as_float(u << 16); }
__device__ __forceinline__ float bhi(unsigned u) { return __uint_as_float(u & 0xffff0000u); }
__device__ __forceinline__ unsigned pk2(float a, float b) {   // RNE bf16 pack (lo=a, hi=b)
    unsigned ua = __float_as_uint(a), ub = __float_as_uint(b);
    ua = (ua + 0x7fffu + ((ua >> 16) & 1u)) >> 16;
    ub = (ub + 0x7fffu + ((ub >> 16) & 1u)) & 0xffff0000u;
    return ua | ub;
}

// ---------------- one GCN layer, 2 threads/node, bf16 LDS staging -------------------
// A: xw' rows (bf16), Bb: activation rows (bf16). 2 barriers/layer.
template <int FIN, bool RELU>
__device__ __forceinline__ void glayer(
    int n, int hf, float di, int nch, const u16* __restrict__ CIDX,
    u16* __restrict__ A, u16* __restrict__ Bb,
    const float* __restrict__ W, const float* __restrict__ Bs, float* xr)
{
    const int ho = hf * 16;
    float acc[16];
    #pragma unroll
    for (int h = 0; h < 16; ++h) acc[h] = 0.f;
    if (hf == 0) {
        #pragma unroll
        for (int f = 0; f < FIN; ++f) {
            float xv = xr[f];
            #pragma unroll
            for (int h = 0; h < 16; ++h) acc[h] = fmaf(xv, W[f * 30 + h], acc[h]);
        }
    } else {
        #pragma unroll
        for (int f = 0; f < FIN; ++f) {
            float xv = xr[f];
            #pragma unroll
            for (int h = 0; h < 14; ++h) acc[h] = fmaf(xv, W[f * 30 + 16 + h], acc[h]);
        }
    }
    #pragma unroll
    for (int h = 0; h < 16; ++h) acc[h] *= di;   // hf=1: acc[14..15] stay 0
    {
        unsigned pk[8];
        #pragma unroll
        for (int q = 0; q < 8; ++q) pk[q] = pk2(acc[2*q], acc[2*q+1]);
        *(uint4*)&A[n * SB + ho]     = make_uint4(pk[0], pk[1], pk[2], pk[3]);
        *(uint4*)&A[n * SB + ho + 8] = make_uint4(pk[4], pk[5], pk[6], pk[7]);
    }
    __syncthreads();                      // (alpha) xw rows ready

    // gather own half of neighbor rows; acc holds the self-loop term (a_ii = 1)
    for (int ch = 0; ch < nch; ++ch) {
        uint4 cwv = *(const uint4*)&CIDX[n * RCAP + ch * 8];
        int j0 = (int)(cwv.x & 0xffffu), j1 = (int)(cwv.x >> 16);
        int j2 = (int)(cwv.y & 0xffffu), j3 = (int)(cwv.y >> 16);
        int j4 = (int)(cwv.z & 0xffffu), j5 = (int)(cwv.z >> 16);
        int j6 = (int)(cwv.w & 0xffffu), j7 = (int)(cwv.w >> 16);
        #define ACCROW(JJ) { \
            const uint4 v0 = *(const uint4*)&A[(JJ) * SB + ho]; \
            const uint4 v1 = *(const uint4*)&A[(JJ) * SB + ho + 8]; \
            acc[0]  += blo(v0.x); acc[1]  += bhi(v0.x); \
            acc[2]  += blo(v0.y); acc[3]  += bhi(v0.y); \
            acc[4]  += blo(v0.z); acc[5]  += bhi(v0.z); \
            acc[6]  += blo(v0.w); acc[7]  += bhi(v0.w); \
            acc[8]  += blo(v1.x); acc[9]  += bhi(v1.x); \
            acc[10] += blo(v1.y); acc[11] += bhi(v1.y); \
            acc[12] += blo(v1.z); acc[13] += bhi(v1.z); \
            acc[14] += blo(v1.w); acc[15] += bhi(v1.w); }
        ACCROW(j0) ACCROW(j1) ACCROW(j2) ACCROW(j3)
        ACCROW(j4) ACCROW(j5) ACCROW(j6) ACCROW(j7)
        #undef ACCROW
    }
    float rr[16];
    if (hf == 0) {
        #pragma unroll
        for (int h = 0; h < 16; ++h) {
            float r = fmaf(di, acc[h], Bs[h]);
            rr[h] = RELU ? fmaxf(r, 0.f) : r;
        }
    } else {
        #pragma unroll
        for (int h = 0; h < 14; ++h) {
            float r = fmaf(di, acc[h], Bs[16 + h]);
            rr[h] = RELU ? fmaxf(r, 0.f) : r;
        }
        rr[14] = 0.f; rr[15] = 0.f;
    }
    {
        unsigned pk[8];
        #pragma unroll
        for (int q = 0; q < 8; ++q) pk[q] = pk2(rr[2*q], rr[2*q+1]);
        *(uint4*)&Bb[n * SB + ho]     = make_uint4(pk[0], pk[1], pk[2], pk[3]);
        *(uint4*)&Bb[n * SB + ho + 8] = make_uint4(pk[4], pk[5], pk[6], pk[7]);
    }
    __syncthreads();                      // (beta) activations ready; gathers on A done

    // reassemble full activation row: own half f32 regs, other half bf16 from Bb
    if (hf == 0) {
        #pragma unroll
        for (int h = 0; h < 16; ++h) xr[h] = rr[h];
        const uint4 v0 = *(const uint4*)&Bb[n * SB + 16];
        const uint4 v1 = *(const uint4*)&Bb[n * SB + 24];
        xr[16] = blo(v0.x); xr[17] = bhi(v0.x); xr[18] = blo(v0.y); xr[19] = bhi(v0.y);
        xr[20] = blo(v0.z); xr[21] = bhi(v0.z); xr[22] = blo(v0.w); xr[23] = bhi(v0.w);
        xr[24] = blo(v1.x); xr[25] = bhi(v1.x); xr[26] = blo(v1.y); xr[27] = bhi(v1.y);
        xr[28] = blo(v1.z); xr[29] = bhi(v1.z);
    } else {
        #pragma unroll
        for (int h = 0; h < 14; ++h) xr[16 + h] = rr[h];
        const uint4 v0 = *(const uint4*)&Bb[n * SB];
        const uint4 v1 = *(const uint4*)&Bb[n * SB + 8];
        xr[0]  = blo(v0.x); xr[1]  = bhi(v0.x); xr[2]  = blo(v0.y); xr[3]  = bhi(v0.y);
        xr[4]  = blo(v0.z); xr[5]  = bhi(v0.z); xr[6]  = blo(v0.w); xr[7]  = bhi(v0.w);
        xr[8]  = blo(v1.x); xr[9]  = bhi(v1.x); xr[10] = blo(v1.y); xr[11] = bhi(v1.y);
        xr[12] = blo(v1.z); xr[13] = bhi(v1.z); xr[14] = blo(v1.w); xr[15] = bhi(v1.w);
    }
    // no barrier: next xw writes A (disjoint from Bb reads); A-gathers drained at beta
}

// ---------------- tail helpers (n = 8,4,2,1 levels, all-LDS) ----------------
__device__ void gcn_small(int n, int t, const float* X, float* XN, float* XW, float* DIS,
                          const float* A, const float* W, const float* Bias, bool relu)
{
    if (t < n) {
        float s = 1.f;
        for (int jj = 0; jj < n; ++jj) if (jj != t) s += A[t * 8 + jj];
        DIS[t] = rsqrtf(fmaxf(1.f, s));
    }
    __syncthreads();
    if (t < n * 30) {
        int i = t / 30, h = t - i * 30;
        float acc = 0.f;
        #pragma unroll
        for (int f = 0; f < 30; ++f) acc += X[i * 30 + f] * W[f * 30 + h];
        XW[t] = acc * DIS[i];
    }
    __syncthreads();
    if (t < n * 30) {
        int i = t / 30, h = t - i * 30;
        float acc = XW[i * 30 + h];
        for (int jj = 0; jj < n; ++jj) if (jj != i) acc += A[i * 8 + jj] * XW[jj * 30 + h];
        float r = DIS[i] * acc + Bias[h];
        if (relu) r = fmaxf(r, 0.f);
        XN[t] = r;
    }
    __syncthreads();
}

__device__ void pool_small(int n, int c, int t, const float* X, const float* A,
                           const float* PW, const float* PB,
                           float* S, float* T, float* LG, float* XN, float* AN)
{
    if (t < n * c) {
        int i = t / c, k = t - i * c;
        float acc = PB[k];
        #pragma unroll
        for (int h = 0; h < 30; ++h) acc += X[i * 30 + h] * PW[h * c + k];
        LG[i * 8 + k] = acc;
    }
    __syncthreads();
    if (t < c) {
        float mx = -1e30f;
        for (int i = 0; i < n; ++i) mx = fmaxf(mx, LG[i * 8 + t]);
        float sm = 0.f;
        for (int i = 0; i < n; ++i) { float e = __expf(LG[i * 8 + t] - mx); LG[i * 8 + t] = e; sm += e; }
        float inv = 1.f / sm;
        for (int i = 0; i < n; ++i) LG[i * 8 + t] *= inv;
    }
    __syncthreads();
    if (t < n) {
        float mx = -1e30f;
        for (int k = 0; k < c; ++k) mx = fmaxf(mx, LG[t * 8 + k]);
        float sm = 0.f;
        for (int k = 0; k < c; ++k) { float e = __expf(LG[t * 8 + k] - mx); S[t * 8 + k] = e; sm += e; }
        float inv = 1.f / sm;
        for (int k = 0; k < c; ++k) S[t * 8 + k] *= inv;
    }
    __syncthreads();
    if (t < c * 30) {
        int k = t / 30, f = t - k * 30;
        float acc = 0.f;
        for (int i = 0; i < n; ++i) acc += S[i * 8 + k] * X[i * 30 + f];
        XN[t] = acc;
    }
    if (t < n * c) {
        int i = t / c, d = t - i * c;
        float acc = 0.f;
        for (int m = 0; m < n; ++m) acc += A[i * 8 + m] * S[m * 8 + d];
        T[i * 8 + d] = acc;
    }
    __syncthreads();
    if (t < c * c) {
        int k = t / c, d = t - k * c;
        float acc = 0.f;
        for (int i = 0; i < n; ++i) acc += S[i * 8 + k] * T[i * 8 + d];
        AN[k * 8 + d] = acc;
    }
    __syncthreads();
}

// ---------------- mega4: 4 GCN + DiffPool0 + tail, 1024 threads, bf16 staging -------
__global__ __launch_bounds__(1024, 4) void mega4_kernel(
    const float* __restrict__ x0,
    const float* __restrict__ W0, const float* __restrict__ Bs0,
    const float* __restrict__ W1, const float* __restrict__ Bs1,
    const float* __restrict__ W2, const float* __restrict__ Bs2,
    const float* __restrict__ W3, const float* __restrict__ Bs3,
    const float* __restrict__ pw, const float* __restrict__ pb,
    const float* cw4, const float* cb4, const float* cw5, const float* cb5,
    const float* cw6, const float* cb6, const float* cw7, const float* cb7,
    const float* pw1, const float* pb1, const float* pw2, const float* pb2,
    const float* pw3, const float* pb3, const float* lw, const float* lb,
    const u16* __restrict__ colidx, const int* __restrict__ rowcnt,
    const float* __restrict__ dis, const float* __restrict__ diagv,
    float* __restrict__ out)
{
    __shared__ __align__(16) u16 CIDX[N_ * RCAP];        // 73728 B; later ltp/red2
    __shared__ __align__(16) u16 XAa[(N_ + 1) * SB];     // 41040 B; later ls/red
    __shared__ __align__(16) u16 XAb[(N_ + 1) * SB];     // 41040 B; keeps x3 (bf16)
    __shared__ float bufX[240], bufY[240], TXW[240], TDIS[8];
    __shared__ float bufA[64], bufB[64], TS[64], TT[64], TLG[64];

    const int b = blockIdx.x, t = threadIdx.x;
    const int n = t & (N_ - 1), hf = t >> 9;

    // ---- P0: bulk-copy neighbor lists global -> LDS (coalesced u32) ----
    {
        const unsigned* g32 = (const unsigned*)(colidx + (size_t)b * N_ * RCAP);
        unsigned* l32 = (unsigned*)CIDX;
        #pragma unroll
        for (int i = 0; i < N_ * RCAP / 2; i += 1024) l32[i + t] = g32[i + t];
    }
    int   nch = rowcnt[(size_t)b * N_ + n];
    float di  = dis  [(size_t)b * N_ + n];
    float dg  = diagv[(size_t)b * N_ + n];
    if (t < 20)              ((unsigned*)&XAa[N_ * SB])[t]      = 0u;  // dummy row 512
    else if (t < 40)         ((unsigned*)&XAb[N_ * SB])[t - 20] = 0u;

    float xr[30];
    {
        const float2* xrow = (const float2*)(x0 + ((size_t)b * N_ + n) * 14);
        #pragma unroll
        for (int k = 0; k < 7; ++k) { float2 v = xrow[k]; xr[2*k] = v.x; xr[2*k+1] = v.y; }
    }

    // ---- 4 GCN layers (first glayer's internal barrier covers the P0 staging) ----
    glayer<14, true >(n, hf, di, nch, CIDX, XAa, XAb, W0, Bs0, xr);
    glayer<30, true >(n, hf, di, nch, CIDX, XAa, XAb, W1, Bs1, xr);
    glayer<30, true >(n, hf, di, nch, CIDX, XAa, XAb, W2, Bs2, xr);
    glayer<30, false>(n, hf, di, nch, CIDX, XAa, XAb, W3, Bs3, xr);  // xr = full x3 row
    // XAb holds x3 (bf16) and is PRESERVED through the pool phase.

    float* ls   = (float*)XAa;            // [513*12] f32 logits / s (row 512 = 0)
    float* red  = (float*)XAa + 6156;     // [4096] f32 xp partials
    float* ltp  = (float*)CIDX;           // [512*8]  f32 A_raw . s (after mid-P4 sync)
    float* red2 = (float*)CIDX + 4096;    // [1024] f32 ap partials

    // P1: logits (each thread does its 4 clusters)
    {
        int c0 = hf * 4;
        float lg[4];
        #pragma unroll
        for (int c = 0; c < 4; ++c) lg[c] = pb[c0 + c];
        #pragma unroll
        for (int h = 0; h < 30; ++h) {
            float xv = xr[h];
            #pragma unroll
            for (int c = 0; c < 4; ++c) lg[c] = fmaf(xv, pw[h * 8 + c0 + c], lg[c]);
        }
        *(float4*)&ls[n * 12 + c0] = make_float4(lg[0], lg[1], lg[2], lg[3]);
        if (t < 12) ls[N_ * 12 + t] = 0.f;
    }
    __syncthreads();
    // P2: softmax over nodes (axis=1), wave w<8 handles cluster c=w
    if (t < 512) {
        int c = t >> 6, lane = t & 63;
        float v[8]; float mx = -1e30f;
        #pragma unroll
        for (int k = 0; k < 8; ++k) { v[k] = ls[(k * 64 + lane) * 12 + c]; mx = fmaxf(mx, v[k]); }
        #pragma unroll
        for (int d = 32; d > 0; d >>= 1) mx = fmaxf(mx, __shfl_xor(mx, d, 64));
        float sm = 0.f;
        #pragma unroll
        for (int k = 0; k < 8; ++k) { v[k] = __expf(v[k] - mx); sm += v[k]; }
        #pragma unroll
        for (int d = 32; d > 0; d >>= 1) sm += __shfl_xor(sm, d, 64);
        float inv = 1.f / sm;
        #pragma unroll
        for (int k = 0; k < 8; ++k) ls[(k * 64 + lane) * 12 + c] = v[k] * inv;
    }
    __syncthreads();
    // P3: softmax over clusters (axis=-1), threads t<512, node t
    if (t < 512) {
        float v[8]; float mx = -1e30f;
        #pragma unroll
        for (int c = 0; c < 8; ++c) { v[c] = ls[t * 12 + c]; mx = fmaxf(mx, v[c]); }
        float sm = 0.f;
        #pragma unroll
        for (int c = 0; c < 8; ++c) { v[c] = __expf(v[c] - mx); sm += v[c]; }
        float inv = 1.f / sm;
        *(float4*)&ls[t * 12]     = make_float4(v[0]*inv, v[1]*inv, v[2]*inv, v[3]*inv);
        *(float4*)&ls[t * 12 + 4] = make_float4(v[4]*inv, v[5]*inv, v[6]*inv, v[7]*inv);
    }
    __syncthreads();
    // P4a: a4 = (A_raw . s)[n][hf*4..hf*4+4) via neighbor list + raw diag
    float a0, a1, a2, a3;
    {
        int d0 = hf * 4;
        const float4 sown = *(const float4*)&ls[n * 12 + d0];
        a0 = dg * sown.x; a1 = dg * sown.y; a2 = dg * sown.z; a3 = dg * sown.w;
        for (int ch = 0; ch < nch; ++ch) {
            uint4 cwv = *(const uint4*)&CIDX[n * RCAP + ch * 8];
            #define LTROW(JJ) { const float4 u0 = *(const float4*)&ls[(JJ) * 12 + d0]; \
                                a0 += u0.x; a1 += u0.y; a2 += u0.z; a3 += u0.w; }
            LTROW((int)(cwv.x & 0xffffu)) LTROW((int)(cwv.x >> 16))
            LTROW((int)(cwv.y & 0xffffu)) LTROW((int)(cwv.y >> 16))
            LTROW((int)(cwv.z & 0xffffu)) LTROW((int)(cwv.z >> 16))
            LTROW((int)(cwv.w & 0xffffu)) LTROW((int)(cwv.w >> 16))
            #undef LTROW
        }
    }
    __syncthreads();   // all CIDX reads done -> safe to overwrite with ltp
    // P4b: write ltp (aliases CIDX)
    *(float4*)&ltp[n * 8 + hf * 4] = make_float4(a0, a1, a2, a3);
    __syncthreads();
    // P6a: xp partials over 16 segs of 32 nodes (x3 bf16 from XAb)
    {
        int seg = t >> 6, cd = t & 63, c = cd >> 3, dd = cd & 7;
        float p0 = 0.f, p1 = 0.f, p2 = 0.f, p3 = 0.f;
        for (int nn = seg * 32; nn < seg * 32 + 32; ++nn) {
            float sv = ls[nn * 12 + c];
            const uint2 xv = *(const uint2*)&XAb[nn * SB + dd * 4];
            p0 = fmaf(sv, blo(xv.x), p0); p1 = fmaf(sv, bhi(xv.x), p1);
            p2 = fmaf(sv, blo(xv.y), p2); p3 = fmaf(sv, bhi(xv.y), p3);
        }
        *(float4*)&red[t * 4] = make_float4(p0, p1, p2, p3);
    }
    // P6b: ap partials
    {
        int seg = t >> 6, c = (t >> 3) & 7, d = t & 7;
        float s1 = 0.f;
        for (int nn = seg * 32; nn < seg * 32 + 32; ++nn)
            s1 = fmaf(ls[nn * 12 + c], ltp[nn * 8 + d], s1);
        red2[t] = s1;
    }
    __syncthreads();
    // P7: final reductions -> bufX (xp), bufA (ap)
    if (t < 240) {
        int c = t / 30, f = t - c * 30, dd = f >> 2, m = f & 3;
        float s1 = 0.f;
        #pragma unroll
        for (int seg = 0; seg < 16; ++seg) s1 += red[(seg * 64 + c * 8 + dd) * 4 + m];
        bufX[t] = s1;
    } else if (t >= 256 && t < 320) {
        int tt = t - 256;
        float s1 = 0.f;
        #pragma unroll
        for (int seg = 0; seg < 16; ++seg) s1 += red2[seg * 64 + tt];
        bufA[tt] = s1;
    }
    __syncthreads();

    // ---- tail: levels n=8,4,2,1 ----
    float *X = bufX, *XN = bufY, *A = bufA, *AN = bufB;
    gcn_small(8, t, X, XN, TXW, TDIS, A, cw4, cb4, true);    { float* tm = X; X = XN; XN = tm; }
    pool_small(8, 4, t, X, A, pw1, pb1, TS, TT, TLG, XN, AN); { float* tm = X; X = XN; XN = tm; tm = A; A = AN; AN = tm; }
    gcn_small(4, t, X, XN, TXW, TDIS, A, cw5, cb5, true);    { float* tm = X; X = XN; XN = tm; }
    pool_small(4, 2, t, X, A, pw2, pb2, TS, TT, TLG, XN, AN); { float* tm = X; X = XN; XN = tm; tm = A; A = AN; AN = tm; }
    gcn_small(2, t, X, XN, TXW, TDIS, A, cw6, cb6, true);    { float* tm = X; X = XN; XN = tm; }
    pool_small(2, 1, t, X, A, pw3, pb3, TS, TT, TLG, XN, AN); { float* tm = X; X = XN; XN = tm; tm = A; A = AN; AN = tm; }
    gcn_small(1, t, X, XN, TXW, TDIS, A, cw7, cb7, true);    { float* tm = X; X = XN; XN = tm; }

    if (t < 2) {
        float acc = lb[t];
        #pragma unroll
        for (int h = 0; h < 30; ++h) acc += X[h] * lw[h * 2 + t];
        out[(size_t)b * 2 + t] = acc;
    }
}

// ---------------- launch ----------------
extern "C" void kernel_launch(void* const* d_in, const int* in_sizes, int n_in,
                              void* d_out, int out_size, void* d_ws, size_t ws_size,
                              hipStream_t stream)
{
    const float* x   = (const float*)d_in[0];
    const float* adj = (const float*)d_in[1];
    const float *cw[8], *cb[8], *pw[4], *pb[4];
    for (int i = 0; i < 8; ++i) { cw[i] = (const float*)d_in[4 + 2 * i]; cb[i] = (const float*)d_in[5 + 2 * i]; }
    for (int i = 0; i < 4; ++i) { pw[i] = (const float*)d_in[20 + 2 * i]; pb[i] = (const float*)d_in[21 + 2 * i]; }
    const float* lw = (const float*)d_in[28];
    const float* lb = (const float*)d_in[29];

    char* ws = (char*)d_ws;
    u16*   colidx = (u16*)(ws + O_COLIDX);
    int*   rowcnt = (int*)(ws + O_ROWCNT);
    float* dis0   = (float*)(ws + O_DIS);
    float* diag0  = (float*)(ws + O_DIAG);

    build_sparse<<<(B_ * N_) / 4, 256, 0, stream>>>(adj, colidx, rowcnt, dis0, diag0);
    mega4_kernel<<<B_, 1024, 0, stream>>>(x,
        cw[0], cb[0], cw[1], cb[1], cw[2], cb[2], cw[3], cb[3],
        pw[0], pb[0],
        cw[4], cb[4], cw[5], cb[5], cw[6], cb[6], cw[7], cb[7],
        pw[1], pb[1], pw[2], pb[2], pw[3], pb[3], lw, lb,
        colidx, rowcnt, dis0, diag0, (float*)d_out);
}

// Round 9
// 204.809 us; speedup vs baseline: 1.0230x; 1.0230x over previous
//
#include <hip/hip_runtime.h>
#include <cstdint>
#include <cstddef>

#define B_ 256
#define N_ 512
#define RCAP 72     // neighbor list stride (u16), padded with dummy row 512
#define SB   40     // bf16 row stride: 80B rows

typedef unsigned short u16;

// ---------------- workspace layout (bytes), ~20 MB ----------------
constexpr size_t O_COLIDX = 0;          // u16 [131072*72]
constexpr size_t O_ROWCNT = 18874368;   // int [131072]  (stores nch = chunk count)
constexpr size_t O_DIS    = 19398656;   // f32 [131072]
constexpr size_t O_DIAG   = 19922944;   // f32 [131072]

// ---------------- pass 1: read adj ONCE (high occupancy), build padded CSR ----------
__global__ __launch_bounds__(256) void build_sparse(
    const float* __restrict__ adj, u16* __restrict__ colidx,
    int* __restrict__ rowcnt, float* __restrict__ dis, float* __restrict__ diagv)
{
    int row  = blockIdx.x * 4 + (threadIdx.x >> 6);
    int lane = threadIdx.x & 63;
    int i    = row & (N_ - 1);
    const float4* arow = (const float4*)(adj + (size_t)row * N_);
    float4 v0 = arow[lane];
    float4 v1 = arow[lane + 64];
    float vals[8] = {v0.x, v0.y, v0.z, v0.w, v1.x, v1.y, v1.z, v1.w};

    float sum = 0.f, dloc = 0.f;
    int cnt = 0;
    #pragma unroll
    for (int k = 0; k < 8; ++k) {
        int jc = (k < 4) ? (lane * 4 + k) : (256 + lane * 4 + (k - 4));
        float v = vals[k];
        if (jc == i) dloc = v;
        else { sum += v; if (v != 0.f) ++cnt; }
    }
    int pre = cnt;
    #pragma unroll
    for (int d = 1; d < 64; d <<= 1) { int y = __shfl_up(pre, d, 64); if (lane >= d) pre += y; }
    int excl  = pre - cnt;
    int total = __shfl(pre, 63, 64);
    #pragma unroll
    for (int d = 32; d > 0; d >>= 1) { sum += __shfl_xor(sum, d, 64); dloc += __shfl_xor(dloc, d, 64); }

    u16* cb = colidx + (size_t)row * RCAP;
    int c2 = 0;
    #pragma unroll
    for (int k = 0; k < 8; ++k) {
        int jc = (k < 4) ? (lane * 4 + k) : (256 + lane * 4 + (k - 4));
        float v = vals[k];
        if (jc != i && v != 0.f) { int p = excl + c2; if (p < RCAP) cb[p] = (u16)jc; ++c2; }
    }
    int base = total > RCAP ? RCAP : total;
    int p1 = base + lane;      if (p1 < RCAP) cb[p1] = (u16)N_;
    int p2 = base + 64 + lane; if (p2 < RCAP) cb[p2] = (u16)N_;
    if (lane == 0) {
        rowcnt[row] = (base + 7) >> 3;                 // chunk count
        dis[row]    = rsqrtf(fmaxf(1.f, sum + 1.f));
        diagv[row]  = dloc;
    }
}

// ---------------- bf16 helpers ----------------
__device__ __forceinline__ float blo(unsigned u) { return __uint_as_float(u << 16); }
__device__ __forceinline__ float bhi(unsigned u) { return __uint_as_float(u & 0xffff0000u); }
__device__ __forceinline__ unsigned pk2(float a, float b) {   // RNE bf16 pack (lo=a, hi=b)
    unsigned ua = __float_as_uint(a), ub = __float_as_uint(b);
    ua = (ua + 0x7fffu + ((ua >> 16) & 1u)) >> 16;
    ub = (ub + 0x7fffu + ((ub >> 16) & 1u)) & 0xffff0000u;
    return ua | ub;
}

// ---------------- one GCN layer, 2 threads/node, bf16 LDS staging -------------------
// A: xw' rows (bf16), Bb: activation rows (bf16). 2 barriers/layer.
template <int FIN, bool RELU>
__device__ __forceinline__ void glayer(
    int n, int hf, float di, int nch, const u16* __restrict__ CIDX,
    u16* __restrict__ A, u16* __restrict__ Bb,
    const float* __restrict__ W, const float* __restrict__ Bs, float* xr)
{
    const int ho = hf * 16;
    float acc[16];
    #pragma unroll
    for (int h = 0; h < 16; ++h) acc[h] = 0.f;
    if (hf == 0) {
        #pragma unroll
        for (int f = 0; f < FIN; ++f) {
            float xv = xr[f];
            #pragma unroll
            for (int h = 0; h < 16; ++h) acc[h] = fmaf(xv, W[f * 30 + h], acc[h]);
        }
    } else {
        #pragma unroll
        for (int f = 0; f < FIN; ++f) {
            float xv = xr[f];
            #pragma unroll
            for (int h = 0; h < 14; ++h) acc[h] = fmaf(xv, W[f * 30 + 16 + h], acc[h]);
        }
    }
    #pragma unroll
    for (int h = 0; h < 16; ++h) acc[h] *= di;   // hf=1: acc[14..15] stay 0
    {
        unsigned pk[8];
        #pragma unroll
        for (int q = 0; q < 8; ++q) pk[q] = pk2(acc[2*q], acc[2*q+1]);
        *(uint4*)&A[n * SB + ho]     = make_uint4(pk[0], pk[1], pk[2], pk[3]);
        *(uint4*)&A[n * SB + ho + 8] = make_uint4(pk[4], pk[5], pk[6], pk[7]);
    }
    __syncthreads();                      // (alpha) xw rows ready

    // gather own half of neighbor rows; acc holds the self-loop term (a_ii = 1)
    for (int ch = 0; ch < nch; ++ch) {
        uint4 cwv = *(const uint4*)&CIDX[n * RCAP + ch * 8];
        int j0 = (int)(cwv.x & 0xffffu), j1 = (int)(cwv.x >> 16);
        int j2 = (int)(cwv.y & 0xffffu), j3 = (int)(cwv.y >> 16);
        int j4 = (int)(cwv.z & 0xffffu), j5 = (int)(cwv.z >> 16);
        int j6 = (int)(cwv.w & 0xffffu), j7 = (int)(cwv.w >> 16);
        #define ACCROW(JJ) { \
            const uint4 v0 = *(const uint4*)&A[(JJ) * SB + ho]; \
            const uint4 v1 = *(const uint4*)&A[(JJ) * SB + ho + 8]; \
            acc[0]  += blo(v0.x); acc[1]  += bhi(v0.x); \
            acc[2]  += blo(v0.y); acc[3]  += bhi(v0.y); \
            acc[4]  += blo(v0.z); acc[5]  += bhi(v0.z); \
            acc[6]  += blo(v0.w); acc[7]  += bhi(v0.w); \
            acc[8]  += blo(v1.x); acc[9]  += bhi(v1.x); \
            acc[10] += blo(v1.y); acc[11] += bhi(v1.y); \
            acc[12] += blo(v1.z); acc[13] += bhi(v1.z); \
            acc[14] += blo(v1.w); acc[15] += bhi(v1.w); }
        ACCROW(j0) ACCROW(j1) ACCROW(j2) ACCROW(j3)
        ACCROW(j4) ACCROW(j5) ACCROW(j6) ACCROW(j7)
        #undef ACCROW
    }
    float rr[16];
    if (hf == 0) {
        #pragma unroll
        for (int h = 0; h < 16; ++h) {
            float r = fmaf(di, acc[h], Bs[h]);
            rr[h] = RELU ? fmaxf(r, 0.f) : r;
        }
    } else {
        #pragma unroll
        for (int h = 0; h < 14; ++h) {
            float r = fmaf(di, acc[h], Bs[16 + h]);
            rr[h] = RELU ? fmaxf(r, 0.f) : r;
        }
        rr[14] = 0.f; rr[15] = 0.f;
    }
    {
        unsigned pk[8];
        #pragma unroll
        for (int q = 0; q < 8; ++q) pk[q] = pk2(rr[2*q], rr[2*q+1]);
        *(uint4*)&Bb[n * SB + ho]     = make_uint4(pk[0], pk[1], pk[2], pk[3]);
        *(uint4*)&Bb[n * SB + ho + 8] = make_uint4(pk[4], pk[5], pk[6], pk[7]);
    }
    __syncthreads();                      // (beta) activations ready; gathers on A done

    // reassemble full activation row: own half f32 regs, other half bf16 from Bb
    if (hf == 0) {
        #pragma unroll
        for (int h = 0; h < 16; ++h) xr[h] = rr[h];
        const uint4 v0 = *(const uint4*)&Bb[n * SB + 16];
        const uint4 v1 = *(const uint4*)&Bb[n * SB + 24];
        xr[16] = blo(v0.x); xr[17] = bhi(v0.x); xr[18] = blo(v0.y); xr[19] = bhi(v0.y);
        xr[20] = blo(v0.z); xr[21] = bhi(v0.z); xr[22] = blo(v0.w); xr[23] = bhi(v0.w);
        xr[24] = blo(v1.x); xr[25] = bhi(v1.x); xr[26] = blo(v1.y); xr[27] = bhi(v1.y);
        xr[28] = blo(v1.z); xr[29] = bhi(v1.z);
    } else {
        #pragma unroll
        for (int h = 0; h < 14; ++h) xr[16 + h] = rr[h];
        const uint4 v0 = *(const uint4*)&Bb[n * SB];
        const uint4 v1 = *(const uint4*)&Bb[n * SB + 8];
        xr[0]  = blo(v0.x); xr[1]  = bhi(v0.x); xr[2]  = blo(v0.y); xr[3]  = bhi(v0.y);
        xr[4]  = blo(v0.z); xr[5]  = bhi(v0.z); xr[6]  = blo(v0.w); xr[7]  = bhi(v0.w);
        xr[8]  = blo(v1.x); xr[9]  = bhi(v1.x); xr[10] = blo(v1.y); xr[11] = bhi(v1.y);
        xr[12] = blo(v1.z); xr[13] = bhi(v1.z); xr[14] = blo(v1.w); xr[15] = bhi(v1.w);
    }
    // no barrier: next xw writes A (disjoint from Bb reads); A-gathers drained at beta
}

// ---------------- tail helpers (n = 8,4,2,1 levels, all-LDS) ----------------
__device__ void gcn_small(int n, int t, const float* X, float* XN, float* XW, float* DIS,
                          const float* A, const float* W, const float* Bias, bool relu)
{
    if (t < n) {
        float s = 1.f;
        for (int jj = 0; jj < n; ++jj) if (jj != t) s += A[t * 8 + jj];
        DIS[t] = rsqrtf(fmaxf(1.f, s));
    }
    __syncthreads();
    if (t < n * 30) {
        int i = t / 30, h = t - i * 30;
        float acc = 0.f;
        #pragma unroll
        for (int f = 0; f < 30; ++f) acc += X[i * 30 + f] * W[f * 30 + h];
        XW[t] = acc * DIS[i];
    }
    __syncthreads();
    if (t < n * 30) {
        int i = t / 30, h = t - i * 30;
        float acc = XW[i * 30 + h];
        for (int jj = 0; jj < n; ++jj) if (jj != i) acc += A[i * 8 + jj] * XW[jj * 30 + h];
        float r = DIS[i] * acc + Bias[h];
        if (relu) r = fmaxf(r, 0.f);
        XN[t] = r;
    }
    __syncthreads();
}

__device__ void pool_small(int n, int c, int t, const float* X, const float* A,
                           const float* PW, const float* PB,
                           float* S, float* T, float* LG, float* XN, float* AN)
{
    if (t < n * c) {
        int i = t / c, k = t - i * c;
        float acc = PB[k];
        #pragma unroll
        for (int h = 0; h < 30; ++h) acc += X[i * 30 + h] * PW[h * c + k];
        LG[i * 8 + k] = acc;
    }
    __syncthreads();
    if (t < c) {
        float mx = -1e30f;
        for (int i = 0; i < n; ++i) mx = fmaxf(mx, LG[i * 8 + t]);
        float sm = 0.f;
        for (int i = 0; i < n; ++i) { float e = __expf(LG[i * 8 + t] - mx); LG[i * 8 + t] = e; sm += e; }
        float inv = 1.f / sm;
        for (int i = 0; i < n; ++i) LG[i * 8 + t] *= inv;
    }
    __syncthreads();
    if (t < n) {
        float mx = -1e30f;
        for (int k = 0; k < c; ++k) mx = fmaxf(mx, LG[t * 8 + k]);
        float sm = 0.f;
        for (int k = 0; k < c; ++k) { float e = __expf(LG[t * 8 + k] - mx); S[t * 8 + k] = e; sm += e; }
        float inv = 1.f / sm;
        for (int k = 0; k < c; ++k) S[t * 8 + k] *= inv;
    }
    __syncthreads();
    if (t < c * 30) {
        int k = t / 30, f = t - k * 30;
        float acc = 0.f;
        for (int i = 0; i < n; ++i) acc += S[i * 8 + k] * X[i * 30 + f];
        XN[t] = acc;
    }
    if (t < n * c) {
        int i = t / c, d = t - i * c;
        float acc = 0.f;
        for (int m = 0; m < n; ++m) acc += A[i * 8 + m] * S[m * 8 + d];
        T[i * 8 + d] = acc;
    }
    __syncthreads();
    if (t < c * c) {
        int k = t / c, d = t - k * c;
        float acc = 0.f;
        for (int i = 0; i < n; ++i) acc += S[i * 8 + k] * T[i * 8 + d];
        AN[k * 8 + d] = acc;
    }
    __syncthreads();
}

// ---------------- mega4: 4 GCN + DiffPool0 + tail, 1024 threads, bf16 staging -------
__global__ __launch_bounds__(1024) void mega4_kernel(
    const float* __restrict__ x0,
    const float* __restrict__ W0, const float* __restrict__ Bs0,
    const float* __restrict__ W1, const float* __restrict__ Bs1,
    const float* __restrict__ W2, const float* __restrict__ Bs2,
    const float* __restrict__ W3, const float* __restrict__ Bs3,
    const float* __restrict__ pw, const float* __restrict__ pb,
    const float* cw4, const float* cb4, const float* cw5, const float* cb5,
    const float* cw6, const float* cb6, const float* cw7, const float* cb7,
    const float* pw1, const float* pb1, const float* pw2, const float* pb2,
    const float* pw3, const float* pb3, const float* lw, const float* lb,
    const u16* __restrict__ colidx, const int* __restrict__ rowcnt,
    const float* __restrict__ dis, const float* __restrict__ diagv,
    float* __restrict__ out)
{
    __shared__ __align__(16) u16 CIDX[N_ * RCAP];        // 73728 B; later ltp/red2
    __shared__ __align__(16) u16 XAa[(N_ + 1) * SB];     // 41040 B; later ls/red
    __shared__ __align__(16) u16 XAb[(N_ + 1) * SB];     // 41040 B; keeps x3 (bf16)
    __shared__ float bufX[240], bufY[240], TXW[240], TDIS[8];
    __shared__ float bufA[64], bufB[64], TS[64], TT[64], TLG[64];

    const int b = blockIdx.x, t = threadIdx.x;
    const int n = t & (N_ - 1), hf = t >> 9;

    // ---- P0: bulk-copy neighbor lists global -> LDS (coalesced u32) ----
    {
        const unsigned* g32 = (const unsigned*)(colidx + (size_t)b * N_ * RCAP);
        unsigned* l32 = (unsigned*)CIDX;
        #pragma unroll
        for (int i = 0; i < N_ * RCAP / 2; i += 1024) l32[i + t] = g32[i + t];
    }
    int   nch = rowcnt[(size_t)b * N_ + n];
    float di  = dis  [(size_t)b * N_ + n];
    float dg  = diagv[(size_t)b * N_ + n];
    if (t < 20)              ((unsigned*)&XAa[N_ * SB])[t]      = 0u;  // dummy row 512
    else if (t < 40)         ((unsigned*)&XAb[N_ * SB])[t - 20] = 0u;

    float xr[30];
    {
        const float2* xrow = (const float2*)(x0 + ((size_t)b * N_ + n) * 14);
        #pragma unroll
        for (int k = 0; k < 7; ++k) { float2 v = xrow[k]; xr[2*k] = v.x; xr[2*k+1] = v.y; }
    }

    // ---- 4 GCN layers (first glayer's internal barrier covers the P0 staging) ----
    glayer<14, true >(n, hf, di, nch, CIDX, XAa, XAb, W0, Bs0, xr);
    glayer<30, true >(n, hf, di, nch, CIDX, XAa, XAb, W1, Bs1, xr);
    glayer<30, true >(n, hf, di, nch, CIDX, XAa, XAb, W2, Bs2, xr);
    glayer<30, false>(n, hf, di, nch, CIDX, XAa, XAb, W3, Bs3, xr);  // xr = full x3 row
    // XAb holds x3 (bf16) and is PRESERVED through the pool phase.

    float* ls   = (float*)XAa;            // [513*12] f32 logits / s (row 512 = 0)
    float* red  = (float*)XAa + 6156;     // [4096] f32 xp partials
    float* ltp  = (float*)CIDX;           // [512*8]  f32 A_raw . s (after mid-P4 sync)
    float* red2 = (float*)CIDX + 4096;    // [1024] f32 ap partials

    // P1: logits (each thread does its 4 clusters)
    {
        int c0 = hf * 4;
        float lg[4];
        #pragma unroll
        for (int c = 0; c < 4; ++c) lg[c] = pb[c0 + c];
        #pragma unroll
        for (int h = 0; h < 30; ++h) {
            float xv = xr[h];
            #pragma unroll
            for (int c = 0; c < 4; ++c) lg[c] = fmaf(xv, pw[h * 8 + c0 + c], lg[c]);
        }
        *(float4*)&ls[n * 12 + c0] = make_float4(lg[0], lg[1], lg[2], lg[3]);
        if (t < 12) ls[N_ * 12 + t] = 0.f;
    }
    __syncthreads();
    // P2: softmax over nodes (axis=1), wave w<8 handles cluster c=w
    if (t < 512) {
        int c = t >> 6, lane = t & 63;
        float v[8]; float mx = -1e30f;
        #pragma unroll
        for (int k = 0; k < 8; ++k) { v[k] = ls[(k * 64 + lane) * 12 + c]; mx = fmaxf(mx, v[k]); }
        #pragma unroll
        for (int d = 32; d > 0; d >>= 1) mx = fmaxf(mx, __shfl_xor(mx, d, 64));
        float sm = 0.f;
        #pragma unroll
        for (int k = 0; k < 8; ++k) { v[k] = __expf(v[k] - mx); sm += v[k]; }
        #pragma unroll
        for (int d = 32; d > 0; d >>= 1) sm += __shfl_xor(sm, d, 64);
        float inv = 1.f / sm;
        #pragma unroll
        for (int k = 0; k < 8; ++k) ls[(k * 64 + lane) * 12 + c] = v[k] * inv;
    }
    __syncthreads();
    // P3: softmax over clusters (axis=-1), threads t<512, node t
    if (t < 512) {
        float v[8]; float mx = -1e30f;
        #pragma unroll
        for (int c = 0; c < 8; ++c) { v[c] = ls[t * 12 + c]; mx = fmaxf(mx, v[c]); }
        float sm = 0.f;
        #pragma unroll
        for (int c = 0; c < 8; ++c) { v[c] = __expf(v[c] - mx); sm += v[c]; }
        float inv = 1.f / sm;
        *(float4*)&ls[t * 12]     = make_float4(v[0]*inv, v[1]*inv, v[2]*inv, v[3]*inv);
        *(float4*)&ls[t * 12 + 4] = make_float4(v[4]*inv, v[5]*inv, v[6]*inv, v[7]*inv);
    }
    __syncthreads();
    // P4a: a4 = (A_raw . s)[n][hf*4..hf*4+4) via neighbor list + raw diag
    float a0, a1, a2, a3;
    {
        int d0 = hf * 4;
        const float4 sown = *(const float4*)&ls[n * 12 + d0];
        a0 = dg * sown.x; a1 = dg * sown.y; a2 = dg * sown.z; a3 = dg * sown.w;
        for (int ch = 0; ch < nch; ++ch) {
            uint4 cwv = *(const uint4*)&CIDX[n * RCAP + ch * 8];
            #define LTROW(JJ) { const float4 u0 = *(const float4*)&ls[(JJ) * 12 + d0]; \
                                a0 += u0.x; a1 += u0.y; a2 += u0.z; a3 += u0.w; }
            LTROW((int)(cwv.x & 0xffffu)) LTROW((int)(cwv.x >> 16))
            LTROW((int)(cwv.y & 0xffffu)) LTROW((int)(cwv.y >> 16))
            LTROW((int)(cwv.z & 0xffffu)) LTROW((int)(cwv.z >> 16))
            LTROW((int)(cwv.w & 0xffffu)) LTROW((int)(cwv.w >> 16))
            #undef LTROW
        }
    }
    __syncthreads();   // all CIDX reads done -> safe to overwrite with ltp
    // P4b: write ltp (aliases CIDX)
    *(float4*)&ltp[n * 8 + hf * 4] = make_float4(a0, a1, a2, a3);
    __syncthreads();
    // P6a: xp partials over 16 segs of 32 nodes (x3 bf16 from XAb)
    {
        int seg = t >> 6, cd = t & 63, c = cd >> 3, dd = cd & 7;
        float p0 = 0.f, p1 = 0.f, p2 = 0.f, p3 = 0.f;
        for (int nn = seg * 32; nn < seg * 32 + 32; ++nn) {
            float sv = ls[nn * 12 + c];
            const uint2 xv = *(const uint2*)&XAb[nn * SB + dd * 4];
            p0 = fmaf(sv, blo(xv.x), p0); p1 = fmaf(sv, bhi(xv.x), p1);
            p2 = fmaf(sv, blo(xv.y), p2); p3 = fmaf(sv, bhi(xv.y), p3);
        }
        *(float4*)&red[t * 4] = make_float4(p0, p1, p2, p3);
    }
    // P6b: ap partials
    {
        int seg = t >> 6, c = (t >> 3) & 7, d = t & 7;
        float s1 = 0.f;
        for (int nn = seg * 32; nn < seg * 32 + 32; ++nn)
            s1 = fmaf(ls[nn * 12 + c], ltp[nn * 8 + d], s1);
        red2[t] = s1;
    }
    __syncthreads();
    // P7: final reductions -> bufX (xp), bufA (ap)
    if (t < 240) {
        int c = t / 30, f = t - c * 30, dd = f >> 2, m = f & 3;
        float s1 = 0.f;
        #pragma unroll
        for (int seg = 0; seg < 16; ++seg) s1 += red[(seg * 64 + c * 8 + dd) * 4 + m];
        bufX[t] = s1;
    } else if (t >= 256 && t < 320) {
        int tt = t - 256;
        float s1 = 0.f;
        #pragma unroll
        for (int seg = 0; seg < 16; ++seg) s1 += red2[seg * 64 + tt];
        bufA[tt] = s1;
    }
    __syncthreads();

    // ---- tail: levels n=8,4,2,1 ----
    float *X = bufX, *XN = bufY, *A = bufA, *AN = bufB;
    gcn_small(8, t, X, XN, TXW, TDIS, A, cw4, cb4, true);    { float* tm = X; X = XN; XN = tm; }
    pool_small(8, 4, t, X, A, pw1, pb1, TS, TT, TLG, XN, AN); { float* tm = X; X = XN; XN = tm; tm = A; A = AN; AN = tm; }
    gcn_small(4, t, X, XN, TXW, TDIS, A, cw5, cb5, true);    { float* tm = X; X = XN; XN = tm; }
    pool_small(4, 2, t, X, A, pw2, pb2, TS, TT, TLG, XN, AN); { float* tm = X; X = XN; XN = tm; tm = A; A = AN; AN = tm; }
    gcn_small(2, t, X, XN, TXW, TDIS, A, cw6, cb6, true);    { float* tm = X; X = XN; XN = tm; }
    pool_small(2, 1, t, X, A, pw3, pb3, TS, TT, TLG, XN, AN); { float* tm = X; X = XN; XN = tm; tm = A; A = AN; AN = tm; }
    gcn_small(1, t, X, XN, TXW, TDIS, A, cw7, cb7, true);    { float* tm = X; X = XN; XN = tm; }

    if (t < 2) {
        float acc = lb[t];
        #pragma unroll
        for (int h = 0; h < 30; ++h) acc += X[h] * lw[h * 2 + t];
        out[(size_t)b * 2 + t] = acc;
    }
}

// ---------------- launch ----------------
extern "C" void kernel_launch(void* const* d_in, const int* in_sizes, int n_in,
                              void* d_out, int out_size, void* d_ws, size_t ws_size,
                              hipStream_t stream)
{
    const float* x   = (const float*)d_in[0];
    const float* adj = (const float*)d_in[1];
    const float *cw[8], *cb[8], *pw[4], *pb[4];
    for (int i = 0; i < 8; ++i) { cw[i] = (const float*)d_in[4 + 2 * i]; cb[i] = (const float*)d_in[5 + 2 * i]; }
    for (int i = 0; i < 4; ++i) { pw[i] = (const float*)d_in[20 + 2 * i]; pb[i] = (const float*)d_in[21 + 2 * i]; }
    const float* lw = (const float*)d_in[28];
    const float* lb = (const float*)d_in[29];

    char* ws = (char*)d_ws;
    u16*   colidx = (u16*)(ws + O_COLIDX);
    int*   rowcnt = (int*)(ws + O_ROWCNT);
    float* dis0   = (float*)(ws + O_DIS);
    float* diag0  = (float*)(ws + O_DIAG);

    build_sparse<<<(B_ * N_) / 4, 256, 0, stream>>>(adj, colidx, rowcnt, dis0, diag0);
    mega4_kernel<<<B_, 1024, 0, stream>>>(x,
        cw[0], cb[0], cw[1], cb[1], cw[2], cb[2], cw[3], cb[3],
        pw[0], pb[0],
        cw[4], cb[4], cw[5], cb[5], cw[6], cb[6], cw[7], cb[7],
        pw[1], pb[1], pw[2], pb[2], pw[3], pb[3], lw, lb,
        colidx, rowcnt, dis0, diag0, (float*)d_out);
}